// Round 7
// baseline (144.247 us; speedup 1.0000x reference)
//
#include <hip/hip_runtime.h>
#include <hip/hip_bf16.h>

#define NN 8192
#define BB 4096
#define DD 256
#define TILE 256
#define NT 32                        // NN / TILE
#define NBLK 528                     // NT*(NT+1)/2 triangular tiles (= 8*66, XCD-bijective)
#define KSCALE 2.8853900817779268f   // 2 * log2(e): exp(sim) = exp2(KSCALE * dot)

typedef __attribute__((ext_vector_type(8))) short short8;
typedef __attribute__((ext_vector_type(4))) float f32x4;

static __device__ __forceinline__ float exp2_fast(float x) {
    float r; asm("v_exp_f32 %0, %1" : "=v"(r) : "v"(x)); return r;
}
static __device__ __forceinline__ ushort f2bf(float x) {
    __hip_bfloat16 h = __float2bfloat16(x);
    return *reinterpret_cast<ushort*>(&h);
}
static __device__ __forceinline__ float bf2f(short u) {
    unsigned int x = (unsigned int)(ushort)u << 16;
    float f; __builtin_memcpy(&f, &x, 4); return f;
}

// Kernel 1: L2-normalize rows of concat(z_i,z_j) -> zn (bf16) and zns = KSCALE*zn (bf16).
// Block 0 also zeroes the output scalar (no memset dispatch needed).
__global__ __launch_bounds__(256) void norm_kernel(const float* __restrict__ zi,
                                                   const float* __restrict__ zj,
                                                   ushort* __restrict__ zn,
                                                   ushort* __restrict__ zns,
                                                   float* __restrict__ out) {
    if (blockIdx.x == 0 && threadIdx.x == 0) out[0] = 0.f;
    int row  = (blockIdx.x * 256 + threadIdx.x) >> 6;
    int lane = threadIdx.x & 63;
    const float* src = (row < BB) ? (zi + (size_t)row * DD)
                                  : (zj + (size_t)(row - BB) * DD);
    float4 v = ((const float4*)src)[lane];
    float ss = v.x * v.x + v.y * v.y + v.z * v.z + v.w * v.w;
    #pragma unroll
    for (int m = 32; m; m >>= 1) ss += __shfl_xor(ss, m, 64);
    float inv = 1.0f / fmaxf(sqrtf(ss), 1e-8f);
    ushort4 o, os;
    o.x  = f2bf(v.x * inv);            o.y  = f2bf(v.y * inv);
    o.z  = f2bf(v.z * inv);            o.w  = f2bf(v.w * inv);
    float invs = inv * KSCALE;
    os.x = f2bf(v.x * invs);           os.y = f2bf(v.y * invs);
    os.z = f2bf(v.z * invs);           os.w = f2bf(v.w * invs);
    ((ushort4*)(zn  + (size_t)row * DD))[lane] = o;
    ((ushort4*)(zns + (size_t)row * DD))[lane] = os;
}

// Kernel 2: triangular 256x256 tile (bi<=bj), 4 waves x 64 rows each.
// A (scaled, 128 VGPR/wave) resident. B: 8 col-subtiles of 32 cols staged via
// global_load_lds into a 3-buffer rotation; counted vmcnt(4), ONE barrier/iter.
// Row-sums -> psum[bj][rows]; col-sums -> psum[bi][cols] (offdiag only).
// Disjoint-write: every psum entry written exactly once, NO atomics.
__global__ __launch_bounds__(256, 2) void sim_kernel(const ushort* __restrict__ zn,
                                                     const ushort* __restrict__ zns,
                                                     float* __restrict__ psum) {
    __shared__ int4  lds4[3][1024];    // 3 bufs x (32 rows x 32 granules x 16B) = 48 KB
    __shared__ float csumW[4][TILE];   // per-wave column partials (4 KB)

    const int tid  = threadIdx.x;
    const int w    = tid >> 6;
    const int lane = tid & 63;
    const int l15  = lane & 15;
    const int lhi  = lane >> 4;

    // XCD-aware swizzle (528 = 8*66, bijective), then triangular decode
    int bid = blockIdx.x;
    int idx = (bid & 7) * (NBLK / 8) + (bid >> 3);
    int bj  = (int)((sqrtf(8.0f * (float)idx + 1.0f) - 1.0f) * 0.5f);
    while ((bj + 1) * (bj + 2) / 2 <= idx) ++bj;
    while (bj * (bj + 1) / 2 > idx) --bj;
    int bi = idx - bj * (bj + 1) / 2;

    const int  rowbase = bi * TILE + w * 64;   // this wave's 64 rows
    const int  colbase = bj * TILE;
    const bool offdiag = (bi != bj);

    // --- A fragments first; wall below keeps them ahead of the stage issues ---
    short8 a[4][8];
    #pragma unroll
    for (int rt = 0; rt < 4; ++rt)
        #pragma unroll
        for (int kk = 0; kk < 8; ++kk)
            a[rt][kk] = *(const short8*)(zns + (size_t)(rowbase + rt * 16 + l15) * DD
                                             + kk * 32 + lhi * 8);
    __builtin_amdgcn_sched_barrier(0);   // wall: A-loads issue before any stage load

    // stage one 32-col subtile (16 KB) into buffer `buf`: 4 gload_lds / thread
    auto STAGE = [&](int buf, int ct) {
        const ushort* base = zn + (size_t)(colbase + ct * 32) * DD;
        #pragma unroll
        for (int i = 0; i < 4; ++i) {
            int d = i * 256 + tid;          // dest granule 0..1023
            int r = d >> 5, c = d & 31;     // staged row, granule-in-row
            const ushort* src = base + (size_t)r * DD + (size_t)((c ^ (r & 7)) * 8);
            __builtin_amdgcn_global_load_lds(
                (__attribute__((address_space(1))) void*)src,
                (__attribute__((address_space(3))) void*)&lds4[buf][i * 256 + w * 64],
                16, 0, 0);
        }
    };

    STAGE(0, 0);
    __builtin_amdgcn_sched_barrier(0);   // wall: stage0 issues strictly before stage1
    STAGE(1, 1);
    __builtin_amdgcn_sched_barrier(0);   // wall: stage1 is the last-4-issued VMEM ops

    f32x4 sume[4];
    #pragma unroll
    for (int rt = 0; rt < 4; ++rt) sume[rt] = (f32x4){0.f, 0.f, 0.f, 0.f};

    #pragma unroll
    for (int ct = 0; ct < 8; ++ct) {
        // own-wave wait: stage ct complete (the 4 loads of stage ct+1 may remain)
        if (ct < 7) asm volatile("s_waitcnt vmcnt(4)" ::: "memory");
        else        asm volatile("s_waitcnt vmcnt(0)" ::: "memory");
        __builtin_amdgcn_s_barrier();        // all waves waited -> tile ct fully in LDS
        __builtin_amdgcn_sched_barrier(0);
        if (ct < 6) STAGE((ct + 2) % 3, ct + 2);   // refill: safe, readers of this buf
                                                   // finished before the barrier above
        const short8* buf = (const short8*)lds4[ct % 3];
        #pragma unroll
        for (int sub = 0; sub < 2; ++sub) {
            const int brow = sub * 16 + l15;
            short8 b[8];
            #pragma unroll
            for (int kk = 0; kk < 8; ++kk)
                b[kk] = buf[brow * 32 + ((kk * 4 + lhi) ^ (brow & 7))];
            f32x4 acc[4];
            #pragma unroll
            for (int rt = 0; rt < 4; ++rt) acc[rt] = (f32x4){0.f, 0.f, 0.f, 0.f};
            #pragma unroll
            for (int kk = 0; kk < 8; ++kk)
                #pragma unroll
                for (int rt = 0; rt < 4; ++rt)
                    acc[rt] = __builtin_amdgcn_mfma_f32_16x16x32_bf16(a[rt][kk], b[kk], acc[rt], 0, 0, 0);
            float cs = 0.f;
            #pragma unroll
            for (int rt = 0; rt < 4; ++rt)
                #pragma unroll
                for (int g = 0; g < 4; ++g) {
                    float e = exp2_fast(acc[rt][g]);
                    sume[rt][g] += e;
                    cs += e;
                }
            if (offdiag) {   // block-uniform branch
                cs += __shfl_xor(cs, 16, 64);     // sum over the 4 lhi row-groups
                cs += __shfl_xor(cs, 32, 64);
                if (lhi == 0) csumW[w][ct * 32 + sub * 16 + l15] = cs;
            }
        }
    }

    // row sums: reduce over the 16 col-lanes, one plain store per row
    #pragma unroll
    for (int rt = 0; rt < 4; ++rt)
        #pragma unroll
        for (int g = 0; g < 4; ++g) {
            float v = sume[rt][g];
            v += __shfl_xor(v, 1, 64); v += __shfl_xor(v, 2, 64);
            v += __shfl_xor(v, 4, 64); v += __shfl_xor(v, 8, 64);
            if (l15 == 0)
                psum[(size_t)bj * NN + rowbase + rt * 16 + lhi * 4 + g] = v;
        }
    // col sums: combine the 4 waves' partials, one plain store per col
    if (offdiag) {
        __syncthreads();
        psum[(size_t)bi * NN + colbase + tid] =
            csumW[0][tid] + csumW[1][tid] + csumW[2][tid] + csumW[3][tid];
    }
}

// Kernel 3: per row r: val = ln(Sum_s psum[s][r] - exp(s_rr)) - pos_r.
// 16 lanes/row, 64 rows/block (1024 thr), one atomicAdd per block (128 total).
__global__ __launch_bounds__(1024) void reduce_kernel(const ushort* __restrict__ zn,
                                                      const ushort* __restrict__ zns,
                                                      const float* __restrict__ psum,
                                                      float* __restrict__ out) {
    const int tid  = threadIdx.x;
    const int rloc = tid >> 4;                 // 0..63
    const int r    = blockIdx.x * 64 + rloc;
    const int l    = tid & 15;

    float S = psum[(size_t)l * NN + r] + psum[(size_t)(16 + l) * NN + r];

    const ushort* zr = zn  + (size_t)r * DD + l * 16;
    const ushort* sr = zns + (size_t)r * DD + l * 16;
    const ushort* pr = zn  + (size_t)(r ^ BB) * DD + l * 16;
    short8 z0 = *(const short8*)zr, z1 = *(const short8*)(zr + 8);
    short8 s0 = *(const short8*)sr, s1 = *(const short8*)(sr + 8);
    short8 p0 = *(const short8*)pr, p1 = *(const short8*)(pr + 8);
    float ds = 0.f, dp = 0.f;
    #pragma unroll
    for (int k = 0; k < 8; ++k) {
        float za = bf2f(z0[k]), zb = bf2f(z1[k]);
        ds += bf2f(s0[k]) * za + bf2f(s1[k]) * zb;   // KSCALE * self-dot
        dp += bf2f(p0[k]) * za + bf2f(p1[k]) * zb;   // dot with positive pair
    }
    #pragma unroll
    for (int m = 1; m < 16; m <<= 1) {
        S  += __shfl_xor(S,  m, 64);
        ds += __shfl_xor(ds, m, 64);
        dp += __shfl_xor(dp, m, 64);
    }
    __shared__ float red[64];
    if (l == 0) red[rloc] = logf(S - exp2_fast(ds)) - 2.0f * dp;
    __syncthreads();
    if (tid < 64) {
        float v = red[tid];
        #pragma unroll
        for (int m = 32; m; m >>= 1) v += __shfl_xor(v, m, 64);
        if (tid == 0) atomicAdd(out, v * (1.0f / NN));
    }
}

extern "C" void kernel_launch(void* const* d_in, const int* in_sizes, int n_in,
                              void* d_out, int out_size, void* d_ws, size_t ws_size,
                              hipStream_t stream) {
    const float* zi = (const float*)d_in[0];
    const float* zj = (const float*)d_in[1];
    float* out = (float*)d_out;

    char* ws = (char*)d_ws;
    ushort* zn   = (ushort*)ws;                          // 4 MB
    ushort* zns  = (ushort*)(ws + (size_t)NN * DD * 2);  // 4 MB
    float*  psum = (float*)(ws + (size_t)NN * DD * 4);   // 32*8192*4 = 1 MB

    norm_kernel<<<NN / 4, 256, 0, stream>>>(zi, zj, zn, zns, out);
    sim_kernel<<<NBLK, 256, 0, stream>>>(zn, zns, psum);
    reduce_kernel<<<NN / 64, 1024, 0, stream>>>(zn, zns, psum, out);
}

// Round 8
// 112.529 us; speedup vs baseline: 1.2819x; 1.2819x over previous
//
#include <hip/hip_runtime.h>
#include <hip/hip_bf16.h>

#define NN 8192
#define BB 4096
#define DD 256
#define TILE 128
#define NT 64                        // NN / TILE
#define NBLK 2080                    // NT*(NT+1)/2 triangular tiles (= 8*260, XCD-bijective)
#define KSCALE 2.8853900817779268f   // 2 * log2(e): exp(sim) = exp2(KSCALE * dot)

typedef __attribute__((ext_vector_type(8))) short short8;
typedef __attribute__((ext_vector_type(4))) float f32x4;

static __device__ __forceinline__ float exp2_fast(float x) {
    float r; asm("v_exp_f32 %0, %1" : "=v"(r) : "v"(x)); return r;
}
static __device__ __forceinline__ ushort f2bf(float x) {
    __hip_bfloat16 h = __float2bfloat16(x);
    return *reinterpret_cast<ushort*>(&h);
}
static __device__ __forceinline__ float bf2f(short u) {
    unsigned int x = (unsigned int)(ushort)u << 16;
    float f; __builtin_memcpy(&f, &x, 4); return f;
}

// Kernel 1: L2-normalize rows of concat(z_i,z_j) -> zn (bf16) and zns = KSCALE*zn (bf16).
// Block 0 also zeroes the output scalar (no memset dispatch needed).
__global__ __launch_bounds__(256) void norm_kernel(const float* __restrict__ zi,
                                                   const float* __restrict__ zj,
                                                   ushort* __restrict__ zn,
                                                   ushort* __restrict__ zns,
                                                   float* __restrict__ out) {
    if (blockIdx.x == 0 && threadIdx.x == 0) out[0] = 0.f;
    int row  = (blockIdx.x * 256 + threadIdx.x) >> 6;
    int lane = threadIdx.x & 63;
    const float* src = (row < BB) ? (zi + (size_t)row * DD)
                                  : (zj + (size_t)(row - BB) * DD);
    float4 v = ((const float4*)src)[lane];
    float ss = v.x * v.x + v.y * v.y + v.z * v.z + v.w * v.w;
    #pragma unroll
    for (int m = 32; m; m >>= 1) ss += __shfl_xor(ss, m, 64);
    float inv = 1.0f / fmaxf(sqrtf(ss), 1e-8f);
    ushort4 o, os;
    o.x  = f2bf(v.x * inv);            o.y  = f2bf(v.y * inv);
    o.z  = f2bf(v.z * inv);            o.w  = f2bf(v.w * inv);
    float invs = inv * KSCALE;
    os.x = f2bf(v.x * invs);           os.y = f2bf(v.y * invs);
    os.z = f2bf(v.z * invs);           os.w = f2bf(v.w * invs);
    ((ushort4*)(zn  + (size_t)row * DD))[lane] = o;
    ((ushort4*)(zns + (size_t)row * DD))[lane] = os;
}

// Kernel 2: m97-structure GEMM tile. Triangular 128x128 tile (bi<=bj).
// 4 waves in 2x2 grid, each computes 64x64 (acc[4][4], 64 VGPR).
// A (zns rows) AND B (zn rows) staged per-K-step (BK=32) into double-buffered
// LDS via global_load_lds; frag reads are LINEAR 1KB wave-reads (conflict-free).
// Epilogue: exp2, row/col sums, disjoint psum writes (64 slots), NO atomics.
__global__ __launch_bounds__(256) void sim_kernel(const ushort* __restrict__ zn,
                                                  const ushort* __restrict__ zns,
                                                  float* __restrict__ psum) {
    __shared__ int4  ldsA[2][512];        // 2 bufs x 128 rows x 32 K bf16 = 16 KB
    __shared__ int4  ldsB[2][512];        // 16 KB
    __shared__ float rsumL[2][2][64];     // (wr, wc, row) 1 KB
    __shared__ float csumL[2][2][64];     // (wc, wr, col) 1 KB

    const int tid  = threadIdx.x;
    const int w    = tid >> 6;
    const int lane = tid & 63;
    const int l15  = lane & 15;
    const int lhi  = lane >> 4;
    const int wr   = w >> 1;              // wave row 0..1 (owns rows wr*64..+64)
    const int wc   = w & 1;               // wave col 0..1

    // XCD-aware swizzle (2080 = 8*260, bijective), then triangular decode
    int bid = blockIdx.x;
    int idx = (bid & 7) * (NBLK / 8) + (bid >> 3);
    int bj  = (int)((sqrtf(8.0f * (float)idx + 1.0f) - 1.0f) * 0.5f);
    while ((bj + 1) * (bj + 2) / 2 <= idx) ++bj;
    while (bj * (bj + 1) / 2 > idx) --bj;
    int bi = idx - bj * (bj + 1) / 2;

    const int  rowt0   = bi * TILE;
    const int  colt0   = bj * TILE;
    const bool offdiag = (bi != bj);

    // stage K-slice k (32 cols) of A-panel (zns) and B-panel (zn) into buf.
    // dest is linear (wave-uniform base + lane*16); src granule d = i*256+tid:
    // row = d>>2, granule-in-row = d&3 (rows are 64B = 4 granules in LDS).
    auto STAGE = [&](int buf, int k) {
        #pragma unroll
        for (int i = 0; i < 2; ++i) {
            int d = i * 256 + tid;
            int r = d >> 2, g = d & 3;
            const ushort* sa = zns + (size_t)(rowt0 + r) * DD + k * 32 + g * 8;
            __builtin_amdgcn_global_load_lds(
                (__attribute__((address_space(1))) void*)sa,
                (__attribute__((address_space(3))) void*)&ldsA[buf][i * 256 + w * 64],
                16, 0, 0);
            const ushort* sb = zn + (size_t)(colt0 + r) * DD + k * 32 + g * 8;
            __builtin_amdgcn_global_load_lds(
                (__attribute__((address_space(1))) void*)sb,
                (__attribute__((address_space(3))) void*)&ldsB[buf][i * 256 + w * 64],
                16, 0, 0);
        }
    };

    f32x4 acc[4][4];
    #pragma unroll
    for (int mi = 0; mi < 4; ++mi)
        #pragma unroll
        for (int ni = 0; ni < 4; ++ni) acc[mi][ni] = (f32x4){0.f, 0.f, 0.f, 0.f};

    STAGE(0, 0);
    __syncthreads();                       // buf0 ready (drains vmcnt)

    #pragma unroll
    for (int k = 0; k < 8; ++k) {
        if (k < 7) STAGE((k + 1) & 1, k + 1);   // prefetch next K-slice
        const short8* bufA = (const short8*)ldsA[k & 1];
        const short8* bufB = (const short8*)ldsB[k & 1];
        short8 af[4], bfr[4];
        // linear reads: row*4 + lhi granules -> contiguous 1KB per fragment
        #pragma unroll
        for (int mi = 0; mi < 4; ++mi)
            af[mi] = bufA[(wr * 64 + mi * 16 + l15) * 4 + lhi];
        #pragma unroll
        for (int ni = 0; ni < 4; ++ni)
            bfr[ni] = bufB[(wc * 64 + ni * 16 + l15) * 4 + lhi];
        #pragma unroll
        for (int mi = 0; mi < 4; ++mi)
            #pragma unroll
            for (int ni = 0; ni < 4; ++ni)
                acc[mi][ni] = __builtin_amdgcn_mfma_f32_16x16x32_bf16(af[mi], bfr[ni], acc[mi][ni], 0, 0, 0);
        __syncthreads();                   // reads retired + prefetch landed
    }

    // ---- epilogue: e = exp2(acc); row sums and col sums ----
    float rpart[4][4];                     // (mi, g)
    float cpart[4];                        // (ni)
    #pragma unroll
    for (int mi = 0; mi < 4; ++mi)
        #pragma unroll
        for (int g = 0; g < 4; ++g) rpart[mi][g] = 0.f;
    #pragma unroll
    for (int ni = 0; ni < 4; ++ni) cpart[ni] = 0.f;

    #pragma unroll
    for (int mi = 0; mi < 4; ++mi)
        #pragma unroll
        for (int ni = 0; ni < 4; ++ni)
            #pragma unroll
            for (int g = 0; g < 4; ++g) {
                float e = exp2_fast(acc[mi][ni][g]);
                rpart[mi][g] += e;
                cpart[ni]    += e;
            }

    // row reduce across the 16 col-lanes (l15); lane l15==0 holds row (mi,lhi,g)
    #pragma unroll
    for (int mi = 0; mi < 4; ++mi)
        #pragma unroll
        for (int g = 0; g < 4; ++g) {
            float v = rpart[mi][g];
            v += __shfl_xor(v, 1, 64); v += __shfl_xor(v, 2, 64);
            v += __shfl_xor(v, 4, 64); v += __shfl_xor(v, 8, 64);
            if (l15 == 0) rsumL[wr][wc][mi * 16 + lhi * 4 + g] = v;
        }
    // col reduce across the 4 row-groups (lhi); lanes lhi==0 hold col ni*16+l15
    #pragma unroll
    for (int ni = 0; ni < 4; ++ni) {
        float v = cpart[ni];
        v += __shfl_xor(v, 16, 64); v += __shfl_xor(v, 32, 64);
        if (lhi == 0) csumL[wc][wr][ni * 16 + l15] = v;
    }
    __syncthreads();

    // disjoint-write: rows -> slot bj; cols -> slot bi (offdiag only).
    if (tid < TILE)
        psum[(size_t)bj * NN + rowt0 + tid] =
            rsumL[tid >> 6][0][tid & 63] + rsumL[tid >> 6][1][tid & 63];
    if (offdiag && tid < TILE)
        psum[(size_t)bi * NN + colt0 + tid] =
            csumL[tid >> 6][0][tid & 63] + csumL[tid >> 6][1][tid & 63];
}

// Kernel 3: per row r: val = ln(Sum_s psum[s][r] - exp(s_rr)) - pos_r.
// 16 lanes/row, 64 rows/block (1024 thr), one atomicAdd per block (128 total).
__global__ __launch_bounds__(1024) void reduce_kernel(const ushort* __restrict__ zn,
                                                      const ushort* __restrict__ zns,
                                                      const float* __restrict__ psum,
                                                      float* __restrict__ out) {
    const int tid  = threadIdx.x;
    const int rloc = tid >> 4;                 // 0..63
    const int r    = blockIdx.x * 64 + rloc;
    const int l    = tid & 15;

    float S = 0.f;
    #pragma unroll
    for (int i = 0; i < 4; ++i) S += psum[(size_t)(i * 16 + l) * NN + r];

    const ushort* zr = zn  + (size_t)r * DD + l * 16;
    const ushort* sr = zns + (size_t)r * DD + l * 16;
    const ushort* pr = zn  + (size_t)(r ^ BB) * DD + l * 16;
    short8 z0 = *(const short8*)zr, z1 = *(const short8*)(zr + 8);
    short8 s0 = *(const short8*)sr, s1 = *(const short8*)(sr + 8);
    short8 p0 = *(const short8*)pr, p1 = *(const short8*)(pr + 8);
    float ds = 0.f, dp = 0.f;
    #pragma unroll
    for (int k = 0; k < 8; ++k) {
        float za = bf2f(z0[k]), zb = bf2f(z1[k]);
        ds += bf2f(s0[k]) * za + bf2f(s1[k]) * zb;   // KSCALE * self-dot
        dp += bf2f(p0[k]) * za + bf2f(p1[k]) * zb;   // dot with positive pair
    }
    #pragma unroll
    for (int m = 1; m < 16; m <<= 1) {
        S  += __shfl_xor(S,  m, 64);
        ds += __shfl_xor(ds, m, 64);
        dp += __shfl_xor(dp, m, 64);
    }
    __shared__ float red[64];
    if (l == 0) red[rloc] = logf(S - exp2_fast(ds)) - 2.0f * dp;
    __syncthreads();
    if (tid < 64) {
        float v = red[tid];
        #pragma unroll
        for (int m = 32; m; m >>= 1) v += __shfl_xor(v, m, 64);
        if (tid == 0) atomicAdd(out, v * (1.0f / NN));
    }
}

extern "C" void kernel_launch(void* const* d_in, const int* in_sizes, int n_in,
                              void* d_out, int out_size, void* d_ws, size_t ws_size,
                              hipStream_t stream) {
    const float* zi = (const float*)d_in[0];
    const float* zj = (const float*)d_in[1];
    float* out = (float*)d_out;

    char* ws = (char*)d_ws;
    ushort* zn   = (ushort*)ws;                          // 4 MB
    ushort* zns  = (ushort*)(ws + (size_t)NN * DD * 2);  // 4 MB
    float*  psum = (float*)(ws + (size_t)NN * DD * 4);   // 64*8192*4 = 2 MB

    norm_kernel<<<NN / 4, 256, 0, stream>>>(zi, zj, zn, zns, out);
    sim_kernel<<<NBLK, 256, 0, stream>>>(zn, zns, psum);
    reduce_kernel<<<NN / 64, 1024, 0, stream>>>(zn, zns, psum, out);
}

// Round 9
// 107.102 us; speedup vs baseline: 1.3468x; 1.0507x over previous
//
#include <hip/hip_runtime.h>
#include <hip/hip_bf16.h>

#define NN 8192
#define BB 4096
#define DD 256
#define TILE 256
#define NT 32                        // NN / TILE
#define NBLK 528                     // NT*(NT+1)/2 triangular tiles (= 8*66, XCD-chunked)
#define BK 32                        // K-step
#define KSCALE 2.8853900817779268f   // 2 * log2(e): exp(sim) = exp2(KSCALE * dot)

typedef __attribute__((ext_vector_type(8))) short short8;
typedef __attribute__((ext_vector_type(4))) float f32x4;

static __device__ __forceinline__ float exp2_fast(float x) {
    float r; asm("v_exp_f32 %0, %1" : "=v"(r) : "v"(x)); return r;
}
static __device__ __forceinline__ ushort f2bf(float x) {
    __hip_bfloat16 h = __float2bfloat16(x);
    return *reinterpret_cast<ushort*>(&h);
}
static __device__ __forceinline__ float bf2f(short u) {
    unsigned int x = (unsigned int)(ushort)u << 16;
    float f; __builtin_memcpy(&f, &x, 4); return f;
}

// Kernel 1: L2-normalize rows of concat(z_i,z_j) -> zn (bf16) and zns = KSCALE*zn (bf16).
// Block 0 also zeroes the output scalar (no memset dispatch needed).
__global__ __launch_bounds__(256) void norm_kernel(const float* __restrict__ zi,
                                                   const float* __restrict__ zj,
                                                   ushort* __restrict__ zn,
                                                   ushort* __restrict__ zns,
                                                   float* __restrict__ out) {
    if (blockIdx.x == 0 && threadIdx.x == 0) out[0] = 0.f;
    int row  = (blockIdx.x * 256 + threadIdx.x) >> 6;
    int lane = threadIdx.x & 63;
    const float* src = (row < BB) ? (zi + (size_t)row * DD)
                                  : (zj + (size_t)(row - BB) * DD);
    float4 v = ((const float4*)src)[lane];
    float ss = v.x * v.x + v.y * v.y + v.z * v.z + v.w * v.w;
    #pragma unroll
    for (int m = 32; m; m >>= 1) ss += __shfl_xor(ss, m, 64);
    float inv = 1.0f / fmaxf(sqrtf(ss), 1e-8f);
    ushort4 o, os;
    o.x  = f2bf(v.x * inv);            o.y  = f2bf(v.y * inv);
    o.z  = f2bf(v.z * inv);            o.w  = f2bf(v.w * inv);
    float invs = inv * KSCALE;
    os.x = f2bf(v.x * invs);           os.y = f2bf(v.y * invs);
    os.z = f2bf(v.z * invs);           os.w = f2bf(v.w * invs);
    ((ushort4*)(zn  + (size_t)row * DD))[lane] = o;
    ((ushort4*)(zns + (size_t)row * DD))[lane] = os;
}

// Kernel 2: triangular 256x256 tile (bi<=bj), 512 thr = 8 waves in 2x4 grid.
// Per wave: 128 rows x 64 cols (acc[8][4], static indices only).
// A(zns) + B(zn) panels staged per BK=32 step into double-buffered LDS via
// global_load_lds (linear dest + inverse-swizzled source); fragment reads use
// slot = r*4 + (lhi ^ ((r>>2)&3)): the 64 lanes of a read then cover 64
// distinct 16B granules spread evenly over all 32 banks (bank-quad index
// (4*(r&1) + g) mod 8 takes each value exactly 8 times -> 16B/cyc/quad, no
// conflict). Counted vmcnt(4): prefetch never drained. Row/col exp-sums ->
// disjoint psum[32][NN] writes, NO atomics.
__global__ __launch_bounds__(512)
__attribute__((amdgpu_waves_per_eu(2, 2)))       // pin 2 waves/SIMD: 256-VGPR cap,
void sim_kernel(const ushort* __restrict__ zn,   // forbid spill-for-occupancy (R7 bug)
                const ushort* __restrict__ zns,
                float* __restrict__ psum) {
    __shared__ int4  lds4[2][2048];       // [buf][A:0..1023 | B:1024..2047] = 64 KB
    __shared__ float rsum[2][4][128];     // (wr, wc, rowlocal) 4 KB
    __shared__ float csum[4][2][64];      // (wc, wr, collocal) 2 KB

    const int tid  = threadIdx.x;
    const int w    = tid >> 6;
    const int lane = tid & 63;
    const int l15  = lane & 15;
    const int lhi  = lane >> 4;
    const int wr   = w >> 2;              // 0..1: owns rows wr*128..+128
    const int wc   = w & 3;               // 0..3: owns cols wc*64..+64

    // XCD-chunked swizzle (528 = 8*66, bijective), then triangular decode
    int bid = blockIdx.x;
    int idx = (bid & 7) * (NBLK / 8) + (bid >> 3);
    int bj  = (int)((sqrtf(8.0f * (float)idx + 1.0f) - 1.0f) * 0.5f);
    while ((bj + 1) * (bj + 2) / 2 <= idx) ++bj;
    while (bj * (bj + 1) / 2 > idx) --bj;
    int bi = idx - bj * (bj + 1) / 2;

    const int  rowt0   = bi * TILE;
    const int  colt0   = bj * TILE;
    const bool offdiag = (bi != bj);

    // stage K-slice k: 512 panel-rows (A then B) x 32 K. 2048 granules of 16B,
    // 4 per thread. Dest slot d linear; source granule = (d&3) ^ ((r>>2)&3).
    auto STAGE = [&](int buf, int k) {
        #pragma unroll
        for (int i = 0; i < 4; ++i) {
            int d = i * 512 + tid;                   // 0..2047
            int s = d & 1023;                        // slot within panel
            int r = s >> 2, gd = s & 3;
            int gs = gd ^ ((r >> 2) & 3);            // inverse swizzle (XOR involution)
            const ushort* srcp = (i < 2)
                ? zns + (size_t)(rowt0 + r) * DD + k * BK + gs * 8
                : zn  + (size_t)(colt0 + r) * DD + k * BK + gs * 8;
            __builtin_amdgcn_global_load_lds(
                (__attribute__((address_space(1))) void*)srcp,
                (__attribute__((address_space(3))) void*)&lds4[buf][i * 512 + w * 64],
                16, 0, 0);
        }
    };

    f32x4 acc[8][4];
    #pragma unroll
    for (int mi = 0; mi < 8; ++mi)
        #pragma unroll
        for (int ni = 0; ni < 4; ++ni) acc[mi][ni] = (f32x4){0.f, 0.f, 0.f, 0.f};

    STAGE(0, 0);
    __builtin_amdgcn_sched_barrier(0);

    #pragma unroll
    for (int k = 0; k < 8; ++k) {
        if (k < 7) STAGE((k + 1) & 1, k + 1);       // prefetch next K-slice
        __builtin_amdgcn_sched_barrier(0);
        // wait own stage-k loads (the 4 of stage k+1 may stay in flight)
        if (k < 7) asm volatile("s_waitcnt vmcnt(4)" ::: "memory");
        else       asm volatile("s_waitcnt vmcnt(0)" ::: "memory");
        __builtin_amdgcn_s_barrier();                // tile k fully in LDS, all waves
        __builtin_amdgcn_sched_barrier(0);

        const short8* bufA = (const short8*)&lds4[k & 1][0];
        const short8* bufB = (const short8*)&lds4[k & 1][1024];
        short8 af[8], bf[4];
        #pragma unroll
        for (int mi = 0; mi < 8; ++mi) {
            int r = wr * 128 + mi * 16 + l15;
            af[mi] = bufA[r * 4 + (lhi ^ ((r >> 2) & 3))];
        }
        #pragma unroll
        for (int ni = 0; ni < 4; ++ni) {
            int r = wc * 64 + ni * 16 + l15;
            bf[ni] = bufB[r * 4 + (lhi ^ ((r >> 2) & 3))];
        }
        #pragma unroll
        for (int mi = 0; mi < 8; ++mi)
            #pragma unroll
            for (int ni = 0; ni < 4; ++ni)
                acc[mi][ni] = __builtin_amdgcn_mfma_f32_16x16x32_bf16(af[mi], bf[ni], acc[mi][ni], 0, 0, 0);
    }

    // ---- epilogue: e = exp2(acc); row and col exp-sums ----
    float rpart[8][4];
    float cpart[4];
    #pragma unroll
    for (int mi = 0; mi < 8; ++mi)
        #pragma unroll
        for (int g = 0; g < 4; ++g) rpart[mi][g] = 0.f;
    #pragma unroll
    for (int ni = 0; ni < 4; ++ni) cpart[ni] = 0.f;

    #pragma unroll
    for (int mi = 0; mi < 8; ++mi)
        #pragma unroll
        for (int ni = 0; ni < 4; ++ni)
            #pragma unroll
            for (int g = 0; g < 4; ++g) {
                float e = exp2_fast(acc[mi][ni][g]);
                rpart[mi][g] += e;
                cpart[ni]    += e;
            }

    // rows: reduce across the 16 col-lanes (l15); C/D row = mi*16 + lhi*4 + g
    #pragma unroll
    for (int mi = 0; mi < 8; ++mi)
        #pragma unroll
        for (int g = 0; g < 4; ++g) {
            float v = rpart[mi][g];
            v += __shfl_xor(v, 1, 64); v += __shfl_xor(v, 2, 64);
            v += __shfl_xor(v, 4, 64); v += __shfl_xor(v, 8, 64);
            if (l15 == 0) rsum[wr][wc][mi * 16 + lhi * 4 + g] = v;
        }
    // cols: reduce across the 4 row-groups (lhi); C/D col = ni*16 + l15
    #pragma unroll
    for (int ni = 0; ni < 4; ++ni) {
        float v = cpart[ni];
        v += __shfl_xor(v, 16, 64); v += __shfl_xor(v, 32, 64);
        if (lhi == 0) csum[wc][wr][ni * 16 + l15] = v;
    }
    __syncthreads();

    // disjoint-write: rows -> slot bj; cols -> slot bi (offdiag only)
    if (tid < TILE) {
        int wrT = tid >> 7, rloc = tid & 127;
        psum[(size_t)bj * NN + rowt0 + tid] =
            rsum[wrT][0][rloc] + rsum[wrT][1][rloc] + rsum[wrT][2][rloc] + rsum[wrT][3][rloc];
        if (offdiag) {
            int wcT = tid >> 6, cloc = tid & 63;
            psum[(size_t)bi * NN + colt0 + tid] = csum[wcT][0][cloc] + csum[wcT][1][cloc];
        }
    }
}

// Kernel 3: per row r: val = ln(Sum_s psum[s][r] - exp(s_rr)) - pos_r.
// 16 lanes/row, 64 rows/block (1024 thr), one atomicAdd per block (128 total).
__global__ __launch_bounds__(1024) void reduce_kernel(const ushort* __restrict__ zn,
                                                      const ushort* __restrict__ zns,
                                                      const float* __restrict__ psum,
                                                      float* __restrict__ out) {
    const int tid  = threadIdx.x;
    const int rloc = tid >> 4;                 // 0..63
    const int r    = blockIdx.x * 64 + rloc;
    const int l    = tid & 15;

    float S = psum[(size_t)l * NN + r] + psum[(size_t)(16 + l) * NN + r];

    const ushort* zr = zn  + (size_t)r * DD + l * 16;
    const ushort* sr = zns + (size_t)r * DD + l * 16;
    const ushort* pr = zn  + (size_t)(r ^ BB) * DD + l * 16;
    short8 z0 = *(const short8*)zr, z1 = *(const short8*)(zr + 8);
    short8 s0 = *(const short8*)sr, s1 = *(const short8*)(sr + 8);
    short8 p0 = *(const short8*)pr, p1 = *(const short8*)(pr + 8);
    float ds = 0.f, dp = 0.f;
    #pragma unroll
    for (int k = 0; k < 8; ++k) {
        float za = bf2f(z0[k]), zb = bf2f(z1[k]);
        ds += bf2f(s0[k]) * za + bf2f(s1[k]) * zb;   // KSCALE * self-dot
        dp += bf2f(p0[k]) * za + bf2f(p1[k]) * zb;   // dot with positive pair
    }
    #pragma unroll
    for (int m = 1; m < 16; m <<= 1) {
        S  += __shfl_xor(S,  m, 64);
        ds += __shfl_xor(ds, m, 64);
        dp += __shfl_xor(dp, m, 64);
    }
    __shared__ float red[64];
    if (l == 0) red[rloc] = logf(S - exp2_fast(ds)) - 2.0f * dp;
    __syncthreads();
    if (tid < 64) {
        float v = red[tid];
        #pragma unroll
        for (int m = 32; m; m >>= 1) v += __shfl_xor(v, m, 64);
        if (tid == 0) atomicAdd(out, v * (1.0f / NN));
    }
}

extern "C" void kernel_launch(void* const* d_in, const int* in_sizes, int n_in,
                              void* d_out, int out_size, void* d_ws, size_t ws_size,
                              hipStream_t stream) {
    const float* zi = (const float*)d_in[0];
    const float* zj = (const float*)d_in[1];
    float* out = (float*)d_out;

    char* ws = (char*)d_ws;
    ushort* zn   = (ushort*)ws;                          // 4 MB
    ushort* zns  = (ushort*)(ws + (size_t)NN * DD * 2);  // 4 MB
    float*  psum = (float*)(ws + (size_t)NN * DD * 4);   // 32*8192*4 = 1 MB

    norm_kernel<<<NN / 4, 256, 0, stream>>>(zi, zj, zn, zns, out);
    sim_kernel<<<NBLK, 512, 0, stream>>>(zn, zns, psum);
    reduce_kernel<<<NN / 64, 1024, 0, stream>>>(zn, zns, psum, out);
}